// Round 1
// baseline (1125.490 us; speedup 1.0000x reference)
//
#include <hip/hip_runtime.h>
#include <math.h>

#define BATCH 512
#define FEAT 512
#define NCLS 1000
#define MSZ 200
#define KP 50
#define KN 20
#define INV_TEMP (1.0f/0.07f)
#define MARGIN 0.5f

// ---------------- K0: init ov = -1, stats = 0 ----------------
__global__ void k_init(int* __restrict__ ov, float* __restrict__ stats) {
    int i = blockIdx.x * blockDim.x + threadIdx.x;
    if (i < NCLS * KP) ov[i] = -1;
    if (i < 6 * BATCH) stats[i] = 0.f;
}

// ---------------- K1: L2-normalize features -> f ----------------
__global__ void k_norm(const float* __restrict__ x, float* __restrict__ f) {
    int row = blockIdx.x;
    int t = threadIdx.x;  // 128 threads, float4 each
    float4 v = ((const float4*)(x + (size_t)row * FEAT))[t];
    float ss = v.x*v.x + v.y*v.y + v.z*v.z + v.w*v.w;
    for (int off = 32; off; off >>= 1) ss += __shfl_down(ss, off);
    __shared__ float w[2];
    if ((t & 63) == 0) w[t >> 6] = ss;
    __syncthreads();
    float inv = 1.f / fmaxf(sqrtf(w[0] + w[1]), 1e-12f);
    float4 o; o.x = v.x*inv; o.y = v.y*inv; o.z = v.z*inv; o.w = v.w*inv;
    ((float4*)(f + (size_t)row * FEAT))[t] = o;
}

// ---------------- K2: rank / group_size / first_idx / override table ----------------
__global__ void k_meta(const int* __restrict__ labels, const int* __restrict__ mptr,
                       int* __restrict__ rank, int* __restrict__ gs,
                       int* __restrict__ fidx, int* __restrict__ ov) {
    __shared__ int lab[BATCH];
    int i = threadIdx.x;
    lab[i] = labels[i];
    __syncthreads();
    int l = lab[i];
    int r = 0, cnt = 0, first = -1;
    for (int j = 0; j < BATCH; j++) {
        if (lab[j] == l) { if (j < i) r++; cnt++; if (first < 0) first = j; }
    }
    rank[i] = r; gs[i] = cnt; fidx[i] = first;
    int wp = (mptr[l] + r) % MSZ;
    if (wp < KP) ov[l * KP + wp] = i;   // duplicate (c,wp) impossible for gs<=200
}

// ---------------- K3: in-batch positive term ----------------
__global__ void k_batchpos(const float* __restrict__ f, const int* __restrict__ labels,
                           const int* __restrict__ rank, const int* __restrict__ gs,
                           const int* __restrict__ fidx,
                           float* __restrict__ psb, float* __restrict__ cb) {
    int i = blockIdx.x;
    int t = threadIdx.x;  // 256
    __shared__ float fi[FEAT];
    for (int d = t; d < FEAT; d += 256) fi[d] = f[(size_t)i * FEAT + d];
    __syncthreads();
    int li = labels[i], fi_first = fidx[i], gsi = gs[i];
    float s = 0.f, c = 0.f;
    if (gsi > 1) {
        for (int j = t; j < BATCH; j += 256) {
            if (labels[j] == li && rank[j] != fi_first) {
                const float4* fj = (const float4*)(f + (size_t)j * FEAT);
                float acc = 0.f;
                #pragma unroll 8
                for (int d = 0; d < FEAT / 4; d++) {
                    float4 a = ((const float4*)fi)[d];
                    float4 b = fj[d];
                    acc += a.x*b.x + a.y*b.y + a.z*b.z + a.w*b.w;
                }
                s += acc * INV_TEMP;
                c += 1.f;
            }
        }
    }
    for (int off = 32; off; off >>= 1) { s += __shfl_down(s, off); c += __shfl_down(c, off); }
    __shared__ float ws[4], wc[4];
    if ((t & 63) == 0) { ws[t >> 6] = s; wc[t >> 6] = c; }
    __syncthreads();
    if (t == 0) {
        psb[i] = ws[0] + ws[1] + ws[2] + ws[3];
        cb[i]  = wc[0] + wc[1] + wc[2] + wc[3];
    }
}

// ---------------- K4: fused S_mem GEMM + reductions ----------------
// grid: (BATCH/64, NCLS); block 256. Block = 64 rows x 64 slots (50 used) of class c.
// thread(tx=t&15, ty=t>>4) owns rows {r*16+ty} x slots {s*16+tx}, r,s in 0..3.
#define TDK 32
__global__ __launch_bounds__(256) void k_main(
    const float* __restrict__ f, const float* __restrict__ bank,
    const int* __restrict__ labels, const int* __restrict__ ov,
    float* __restrict__ own_sum, float* __restrict__ all_sum,
    float* __restrict__ hard_sum, float* __restrict__ hard_cnt)
{
    int c = blockIdx.y;
    int rowbase = blockIdx.x * 64;
    int t = threadIdx.x;
    int tx = t & 15, ty = t >> 4;

    __shared__ __align__(16) float fA[64][TDK + 4];  // stride 36: breaks pow2 conflicts
    __shared__ __align__(16) float fB[64][TDK + 4];
    __shared__ const float* ptrs[64];

    if (t < 64) {
        const float* p = nullptr;
        if (t < KP) {
            int o = ov[c * KP + t];
            p = (o >= 0) ? (f + (size_t)o * FEAT)
                         : (bank + ((size_t)c * MSZ + t) * FEAT);
        }
        ptrs[t] = p;
    }
    __syncthreads();

    float acc[4][4];
    #pragma unroll
    for (int r = 0; r < 4; r++)
        #pragma unroll
        for (int s = 0; s < 4; s++) acc[r][s] = 0.f;

    int lrow = t >> 2;            // 0..63: row/slot this thread stages
    int lcol8 = (t & 3) * 8;      // 0,8,16,24
    const float* fArow = f + (size_t)(rowbase + lrow) * FEAT + lcol8;
    const float* pB = ptrs[lrow];

    for (int d0 = 0; d0 < FEAT; d0 += TDK) {
        float4 a0 = *(const float4*)(fArow + d0);
        float4 a1 = *(const float4*)(fArow + d0 + 4);
        float4 b0 = make_float4(0.f, 0.f, 0.f, 0.f), b1 = b0;
        if (pB) {
            b0 = *(const float4*)(pB + d0 + lcol8);
            b1 = *(const float4*)(pB + d0 + lcol8 + 4);
        }
        __syncthreads();
        *(float4*)&fA[lrow][lcol8]     = a0;
        *(float4*)&fA[lrow][lcol8 + 4] = a1;
        *(float4*)&fB[lrow][lcol8]     = b0;
        *(float4*)&fB[lrow][lcol8 + 4] = b1;
        __syncthreads();

        #pragma unroll
        for (int kk = 0; kk < TDK; kk += 4) {
            float4 av[4], bv[4];
            #pragma unroll
            for (int r = 0; r < 4; r++) av[r] = *(const float4*)&fA[r * 16 + ty][kk];
            #pragma unroll
            for (int s = 0; s < 4; s++) bv[s] = *(const float4*)&fB[s * 16 + tx][kk];
            #pragma unroll
            for (int r = 0; r < 4; r++)
                #pragma unroll
                for (int s = 0; s < 4; s++)
                    acc[r][s] += av[r].x*bv[s].x + av[r].y*bv[s].y
                               + av[r].z*bv[s].z + av[r].w*bv[s].w;
        }
    }

    // ---- fused epilogue: per-row masked reductions ----
    #pragma unroll
    for (int r = 0; r < 4; r++) {
        int row = rowbase + r * 16 + ty;
        bool isown = (labels[row] == c);     // uniform across tx
        float own = 0.f, alls = 0.f, hs = 0.f, hc = 0.f;
        #pragma unroll
        for (int s = 0; s < 4; s++) {
            int slot = s * 16 + tx;
            float sim = acc[r][s] * INV_TEMP;
            if (isown) {
                if (slot < KP) own += sim;
            } else if (slot < KN) {
                alls += sim;
                if (sim > MARGIN) { hs += sim; hc += 1.f; }
            }
        }
        for (int off = 8; off; off >>= 1) {
            own  += __shfl_down(own,  off, 16);
            alls += __shfl_down(alls, off, 16);
            hs   += __shfl_down(hs,   off, 16);
            hc   += __shfl_down(hc,   off, 16);
        }
        if (tx == 0) {
            if (isown) {
                atomicAdd(&own_sum[row], own);
            } else {
                atomicAdd(&all_sum[row], alls);
                if (hc > 0.f) {
                    atomicAdd(&hard_sum[row], hs);
                    atomicAdd(&hard_cnt[row], hc);
                }
            }
        }
    }
}

// ---------------- K5: per-row loss + mean ----------------
__global__ void k_final(const float* __restrict__ own_sum, const float* __restrict__ all_sum,
                        const float* __restrict__ hard_sum, const float* __restrict__ hard_cnt,
                        const float* __restrict__ psb, const float* __restrict__ cb,
                        float* __restrict__ out) {
    int i = threadIdx.x;  // 512
    float pos = -(psb[i] + own_sum[i]) / (cb[i] + (float)KP);
    float hcnt = hard_cnt[i];
    float neg = (hcnt > 0.f) ? hard_sum[i] / fmaxf(hcnt, 1.f)
                             : all_sum[i] / ((float)(NCLS - 1) * (float)KN);
    float v = pos + neg;
    for (int off = 32; off; off >>= 1) v += __shfl_down(v, off);
    __shared__ float w[8];
    if ((i & 63) == 0) w[i >> 6] = v;
    __syncthreads();
    if (i == 0) {
        float s = 0.f;
        for (int k = 0; k < 8; k++) s += w[k];
        out[0] = s / (float)BATCH;
    }
}

extern "C" void kernel_launch(void* const* d_in, const int* in_sizes, int n_in,
                              void* d_out, int out_size, void* d_ws, size_t ws_size,
                              hipStream_t stream) {
    const float* features = (const float*)d_in[0];
    const int*   labels   = (const int*)d_in[1];
    const float* bank     = (const float*)d_in[2];
    const int*   mptr     = (const int*)d_in[3];
    float* out = (float*)d_out;

    // ws layout
    float* f        = (float*)d_ws;                 // 512*512
    int*   rank     = (int*)(f + BATCH * FEAT);     // 512
    int*   gs       = rank + BATCH;                 // 512
    int*   fidx     = gs + BATCH;                   // 512
    int*   ov       = fidx + BATCH;                 // 1000*50
    float* own_sum  = (float*)(ov + NCLS * KP);     // 512  (stats block: 6*512 contiguous)
    float* all_sum  = own_sum + BATCH;
    float* hard_sum = all_sum + BATCH;
    float* hard_cnt = hard_sum + BATCH;
    float* psb      = hard_cnt + BATCH;
    float* cb       = psb + BATCH;

    k_init<<<(NCLS * KP + 255) / 256, 256, 0, stream>>>(ov, own_sum);
    k_norm<<<BATCH, 128, 0, stream>>>(features, f);
    k_meta<<<1, BATCH, 0, stream>>>(labels, mptr, rank, gs, fidx, ov);
    k_batchpos<<<BATCH, 256, 0, stream>>>(f, labels, rank, gs, fidx, psb, cb);
    dim3 g4(BATCH / 64, NCLS);
    k_main<<<g4, 256, 0, stream>>>(f, bank, labels, ov, own_sum, all_sum, hard_sum, hard_cnt);
    k_final<<<1, BATCH, 0, stream>>>(own_sum, all_sum, hard_sum, hard_cnt, psb, cb, out);
}

// Round 2
// 548.851 us; speedup vs baseline: 2.0506x; 2.0506x over previous
//
#include <hip/hip_runtime.h>
#include <hip/hip_bf16.h>
#include <math.h>

#define BATCH 512
#define FEAT 512
#define NCLS 1000
#define MSZ 200
#define KP 50
#define KN 20
#define INV_TEMP (1.0f/0.07f)
#define MARGIN 0.5f
#define NBROWS 20032          // NCLS*KN (=20000) padded to multiple of 64
#define NCB 313               // col blocks of 64
#define NPART (NCB*2)         // partials per row: colblock x wave-col

typedef __attribute__((ext_vector_type(8))) short short8;
typedef __attribute__((ext_vector_type(4))) float f32x4;

__device__ __forceinline__ unsigned short f2bf(float x) {
    __hip_bfloat16 h = __float2bfloat16(x);   // RNE
    return *reinterpret_cast<unsigned short*>(&h);
}

__device__ __forceinline__ void gload_lds16(const void* g, void* l) {
    __builtin_amdgcn_global_load_lds(
        (const __attribute__((address_space(1))) void*)g,
        (__attribute__((address_space(3))) void*)l, 16, 0, 0);
}

// ---------------- K0: init ov = -1, own_sum = 0 ----------------
__global__ void k_init(int* __restrict__ ov, float* __restrict__ own_sum) {
    int i = blockIdx.x * blockDim.x + threadIdx.x;
    if (i < NCLS * KP) ov[i] = -1;
    if (i < BATCH) own_sum[i] = 0.f;
}

// ---------------- K1: L2-normalize features -> f (fp32) + fb (bf16) ----------------
__global__ void k_norm(const float* __restrict__ x, float* __restrict__ f,
                       unsigned short* __restrict__ fb) {
    int row = blockIdx.x;
    int t = threadIdx.x;  // 128 threads, float4 each
    float4 v = ((const float4*)(x + (size_t)row * FEAT))[t];
    float ss = v.x*v.x + v.y*v.y + v.z*v.z + v.w*v.w;
    for (int off = 32; off; off >>= 1) ss += __shfl_down(ss, off);
    __shared__ float w[2];
    if ((t & 63) == 0) w[t >> 6] = ss;
    __syncthreads();
    float inv = 1.f / fmaxf(sqrtf(w[0] + w[1]), 1e-12f);
    float4 o; o.x = v.x*inv; o.y = v.y*inv; o.z = v.z*inv; o.w = v.w*inv;
    ((float4*)(f + (size_t)row * FEAT))[t] = o;
    unsigned long long pk = (unsigned long long)f2bf(o.x)
                          | ((unsigned long long)f2bf(o.y) << 16)
                          | ((unsigned long long)f2bf(o.z) << 32)
                          | ((unsigned long long)f2bf(o.w) << 48);
    *(unsigned long long*)(fb + (size_t)row * FEAT + t * 4) = pk;
}

// ---------------- K2: rank / group_size / first_idx / override table ----------------
__global__ void k_meta(const int* __restrict__ labels, const int* __restrict__ mptr,
                       int* __restrict__ rank, int* __restrict__ gs,
                       int* __restrict__ fidx, int* __restrict__ ov) {
    __shared__ int lab[BATCH];
    int i = threadIdx.x;
    lab[i] = labels[i];
    __syncthreads();
    int l = lab[i];
    int r = 0, cnt = 0, first = -1;
    for (int j = 0; j < BATCH; j++) {
        if (lab[j] == l) { if (j < i) r++; cnt++; if (first < 0) first = j; }
    }
    rank[i] = r; gs[i] = cnt; fidx[i] = first;
    int wp = (mptr[l] + r) % MSZ;
    if (wp < KP) ov[l * KP + wp] = i;
}

// ---------------- K3: build Bm (bf16, overridden bank[:, :KN], padded rows zeroed) ----
__global__ __launch_bounds__(256) void k_conv(const float* __restrict__ f,
                                              const float* __restrict__ bank,
                                              const int* __restrict__ ov,
                                              unsigned short* __restrict__ Bm) {
    int g = blockIdx.x * 4 + (threadIdx.x >> 6);   // one wave per row
    int lane = threadIdx.x & 63;
    unsigned short* dst = Bm + (size_t)g * FEAT + lane * 8;
    if (g >= NCLS * KN) {
        short8 z = {0,0,0,0,0,0,0,0};
        *(short8*)dst = z;
        return;
    }
    int c = g / KN, s = g - c * KN;
    int o = ov[c * KP + s];
    const float* src = (o >= 0) ? (f + (size_t)o * FEAT)
                                : (bank + ((size_t)c * MSZ + s) * FEAT);
    const float4* s4 = (const float4*)(src + lane * 8);
    float4 v0 = s4[0], v1 = s4[1];
    short8 out;
    out[0] = (short)f2bf(v0.x); out[1] = (short)f2bf(v0.y);
    out[2] = (short)f2bf(v0.z); out[3] = (short)f2bf(v0.w);
    out[4] = (short)f2bf(v1.x); out[5] = (short)f2bf(v1.y);
    out[6] = (short)f2bf(v1.z); out[7] = (short)f2bf(v1.w);
    *(short8*)dst = out;
}

// ---------------- K4: in-batch positive term (fp32, exact) ----------------
__global__ void k_batchpos(const float* __restrict__ f, const int* __restrict__ labels,
                           const int* __restrict__ rank, const int* __restrict__ gs,
                           const int* __restrict__ fidx,
                           float* __restrict__ psb, float* __restrict__ cb) {
    int i = blockIdx.x;
    int t = threadIdx.x;  // 256
    __shared__ float fi[FEAT];
    for (int d = t; d < FEAT; d += 256) fi[d] = f[(size_t)i * FEAT + d];
    __syncthreads();
    int li = labels[i], fi_first = fidx[i], gsi = gs[i];
    float s = 0.f, c = 0.f;
    if (gsi > 1) {
        for (int j = t; j < BATCH; j += 256) {
            if (labels[j] == li && rank[j] != fi_first) {
                const float4* fj = (const float4*)(f + (size_t)j * FEAT);
                float acc = 0.f;
                #pragma unroll 8
                for (int d = 0; d < FEAT / 4; d++) {
                    float4 a = ((const float4*)fi)[d];
                    float4 b = fj[d];
                    acc += a.x*b.x + a.y*b.y + a.z*b.z + a.w*b.w;
                }
                s += acc * INV_TEMP;
                c += 1.f;
            }
        }
    }
    for (int off = 32; off; off >>= 1) { s += __shfl_down(s, off); c += __shfl_down(c, off); }
    __shared__ float ws[4], wc[4];
    if ((t & 63) == 0) { ws[t >> 6] = s; wc[t >> 6] = c; }
    __syncthreads();
    if (t == 0) {
        psb[i] = ws[0] + ws[1] + ws[2] + ws[3];
        cb[i]  = wc[0] + wc[1] + wc[2] + wc[3];
    }
}

// ---------------- K5: bf16 MFMA GEMM 512 x NBROWS x 512, fused epilogue ----------------
// Tile 128 rows x 64 cols, BK=64. 4 waves in 2x2: wr = row-half, wc = col-half(32).
#define BK 64
__global__ __launch_bounds__(256) void k_main(
    const unsigned short* __restrict__ fb, const unsigned short* __restrict__ Bm,
    const int* __restrict__ labels,
    float* __restrict__ own_sum,
    float* __restrict__ pa_all, float* __restrict__ pa_hs, float* __restrict__ pa_hc)
{
    int cb = blockIdx.y;
    int rbase = blockIdx.x * 128;
    int t = threadIdx.x;
    int w = t >> 6, lane = t & 63;
    int wr = w >> 1, wc = w & 1;
    int ln15 = lane & 15, quad = lane >> 4;

    __shared__ __align__(16) unsigned short As[128][BK];  // 16 KB, no pad (DMA dest)
    __shared__ __align__(16) unsigned short Bs[64][BK];   // 8 KB

    f32x4 acc[4][2];
    #pragma unroll
    for (int i = 0; i < 4; i++)
        #pragma unroll
        for (int j = 0; j < 2; j++) acc[i][j] = (f32x4){0.f, 0.f, 0.f, 0.f};

    // staging: linear byte L in tile = call*4096 + w*1024 + lane*16
    const char* aSrc[4]; void* aDst[4];
    const char* bSrc[2]; void* bDst[2];
    #pragma unroll
    for (int q = 0; q < 4; q++) {
        unsigned int L = q * 4096 + w * 1024 + lane * 16;
        int row = L >> 7;                 // 128 B per LDS row (BK=64 bf16)
        int part = L & 127;
        aSrc[q] = (const char*)fb + (size_t)(rbase + row) * (FEAT * 2) + part;
        aDst[q] = (char*)&As[0][0] + (q * 4096 + w * 1024);
    }
    #pragma unroll
    for (int q = 0; q < 2; q++) {
        unsigned int L = q * 4096 + w * 1024 + lane * 16;
        int row = L >> 7;
        int part = L & 127;
        bSrc[q] = (const char*)Bm + (size_t)(cb * 64 + row) * (FEAT * 2) + part;
        bDst[q] = (char*)&Bs[0][0] + (q * 4096 + w * 1024);
    }

    for (int k0 = 0; k0 < FEAT; k0 += BK) {
        __syncthreads();  // previous chunk's ds_reads done
        #pragma unroll
        for (int q = 0; q < 4; q++) gload_lds16(aSrc[q] + k0 * 2, aDst[q]);
        #pragma unroll
        for (int q = 0; q < 2; q++) gload_lds16(bSrc[q] + k0 * 2, bDst[q]);
        __syncthreads();  // vmcnt(0) drain -> DMA visible

        #pragma unroll
        for (int kh = 0; kh < BK; kh += 32) {
            short8 a[4], b[2];
            #pragma unroll
            for (int i = 0; i < 4; i++)
                a[i] = *(const short8*)&As[wr * 64 + i * 16 + ln15][kh + quad * 8];
            #pragma unroll
            for (int j = 0; j < 2; j++)
                b[j] = *(const short8*)&Bs[wc * 32 + j * 16 + ln15][kh + quad * 8];
            #pragma unroll
            for (int i = 0; i < 4; i++)
                #pragma unroll
                for (int j = 0; j < 2; j++)
                    acc[i][j] = __builtin_amdgcn_mfma_f32_16x16x32_bf16(a[i], b[j], acc[i][j], 0, 0, 0);
        }
    }

    // epilogue: C/D map col=lane&15, row=quad*4+reg (m89/m91 verified)
    #pragma unroll
    for (int i = 0; i < 4; i++) {
        #pragma unroll
        for (int r = 0; r < 4; r++) {
            int grow = rbase + wr * 64 + i * 16 + quad * 4 + r;
            int lab = labels[grow];
            float own = 0.f, alls = 0.f, hs = 0.f, hc = 0.f;
            #pragma unroll
            for (int j = 0; j < 2; j++) {
                int gcol = cb * 64 + wc * 32 + j * 16 + ln15;
                float sim = acc[i][j][r] * INV_TEMP;
                if (gcol < NCLS * KN) {
                    int c = gcol / KN;
                    if (c == lab) {
                        own += sim;
                    } else {
                        alls += sim;
                        if (sim > MARGIN) { hs += sim; hc += 1.f; }
                    }
                }
            }
            #pragma unroll
            for (int off = 8; off; off >>= 1) {
                own  += __shfl_down(own,  off, 16);
                alls += __shfl_down(alls, off, 16);
                hs   += __shfl_down(hs,   off, 16);
                hc   += __shfl_down(hc,   off, 16);
            }
            if (ln15 == 0) {
                size_t pidx = (size_t)(cb * 2 + wc) * BATCH + grow;
                pa_all[pidx] = alls; pa_hs[pidx] = hs; pa_hc[pidx] = hc;
                if (own != 0.f) atomicAdd(&own_sum[grow], own);
            }
        }
    }
}

// ---------------- K6: own-class slots KN..KP-1 (fp32) ----------------
__global__ __launch_bounds__(256) void k_ownextra(
    const float* __restrict__ f, const float* __restrict__ bank,
    const int* __restrict__ labels, const int* __restrict__ ov,
    float* __restrict__ own2)
{
    int row = blockIdx.x;
    int t = threadIdx.x, w = t >> 6, lane = t & 63;
    int c = labels[row];
    float a0=0,a1=0,a2=0,a3=0,a4=0,a5=0,a6=0,a7=0;   // vec-sum over slots (lane's 8 dims)
    for (int s = KN + w; s < KP; s += 4) {
        int o = ov[c * KP + s];
        const float* src = (o >= 0) ? (f + (size_t)o * FEAT)
                                    : (bank + ((size_t)c * MSZ + s) * FEAT);
        const float4* s4 = (const float4*)(src + lane * 8);
        float4 v0 = s4[0], v1 = s4[1];
        a0 += v0.x; a1 += v0.y; a2 += v0.z; a3 += v0.w;
        a4 += v1.x; a5 += v1.y; a6 += v1.z; a7 += v1.w;
    }
    const float4* f4 = (const float4*)(f + (size_t)row * FEAT + lane * 8);
    float4 fa = f4[0], fbv = f4[1];
    float p = fa.x*a0 + fa.y*a1 + fa.z*a2 + fa.w*a3
            + fbv.x*a4 + fbv.y*a5 + fbv.z*a6 + fbv.w*a7;
    for (int off = 32; off; off >>= 1) p += __shfl_down(p, off);
    __shared__ float ws[4];
    if (lane == 0) ws[w] = p;
    __syncthreads();
    if (t == 0) own2[row] = (ws[0] + ws[1] + ws[2] + ws[3]) * INV_TEMP;
}

// ---------------- K7: reduce neg partials ----------------
__global__ void k_reduce(const float* __restrict__ pa_all, const float* __restrict__ pa_hs,
                         const float* __restrict__ pa_hc,
                         float* __restrict__ all_sum, float* __restrict__ hard_sum,
                         float* __restrict__ hard_cnt)
{
    int row = blockIdx.x;
    int t = threadIdx.x;  // 256
    float a = 0.f, h = 0.f, hc = 0.f;
    for (int p = t; p < NPART; p += 256) {
        size_t idx = (size_t)p * BATCH + row;
        a += pa_all[idx]; h += pa_hs[idx]; hc += pa_hc[idx];
    }
    for (int off = 32; off; off >>= 1) {
        a += __shfl_down(a, off); h += __shfl_down(h, off); hc += __shfl_down(hc, off);
    }
    __shared__ float wa[4], wh[4], wcn[4];
    int w = t >> 6, lane = t & 63;
    if (lane == 0) { wa[w] = a; wh[w] = h; wcn[w] = hc; }
    __syncthreads();
    if (t == 0) {
        all_sum[row]  = wa[0] + wa[1] + wa[2] + wa[3];
        hard_sum[row] = wh[0] + wh[1] + wh[2] + wh[3];
        hard_cnt[row] = wcn[0] + wcn[1] + wcn[2] + wcn[3];
    }
}

// ---------------- K8: per-row loss + mean ----------------
__global__ void k_final(const float* __restrict__ own_sum, const float* __restrict__ own2,
                        const float* __restrict__ all_sum,
                        const float* __restrict__ hard_sum, const float* __restrict__ hard_cnt,
                        const float* __restrict__ psb, const float* __restrict__ cb,
                        float* __restrict__ out) {
    int i = threadIdx.x;  // 512
    float pos = -(psb[i] + own_sum[i] + own2[i]) / (cb[i] + (float)KP);
    float hcnt = hard_cnt[i];
    float neg = (hcnt > 0.f) ? hard_sum[i] / fmaxf(hcnt, 1.f)
                             : all_sum[i] / ((float)(NCLS - 1) * (float)KN);
    float v = pos + neg;
    for (int off = 32; off; off >>= 1) v += __shfl_down(v, off);
    __shared__ float w[8];
    if ((i & 63) == 0) w[i >> 6] = v;
    __syncthreads();
    if (i == 0) {
        float s = 0.f;
        for (int k = 0; k < 8; k++) s += w[k];
        out[0] = s / (float)BATCH;
    }
}

extern "C" void kernel_launch(void* const* d_in, const int* in_sizes, int n_in,
                              void* d_out, int out_size, void* d_ws, size_t ws_size,
                              hipStream_t stream) {
    const float* features = (const float*)d_in[0];
    const int*   labels   = (const int*)d_in[1];
    const float* bank     = (const float*)d_in[2];
    const int*   mptr     = (const int*)d_in[3];
    float* out = (float*)d_out;

    // ws layout (all 16B-aligned)
    float* f            = (float*)d_ws;                         // 512*512 f32
    unsigned short* fb  = (unsigned short*)(f + BATCH * FEAT);  // 512*512 bf16
    unsigned short* Bm  = fb + (size_t)BATCH * FEAT;            // NBROWS*512 bf16
    int*   ov           = (int*)(Bm + (size_t)NBROWS * FEAT);   // 1000*50
    int*   rank         = ov + NCLS * KP;                       // 512
    int*   gs           = rank + BATCH;
    int*   fidx         = gs + BATCH;
    float* own_sum      = (float*)(fidx + BATCH);
    float* own2         = own_sum + BATCH;
    float* all_sum      = own2 + BATCH;
    float* hard_sum     = all_sum + BATCH;
    float* hard_cnt     = hard_sum + BATCH;
    float* psb          = hard_cnt + BATCH;
    float* cb           = psb + BATCH;
    float* pa_all       = cb + BATCH;                           // NPART*512 each
    float* pa_hs        = pa_all + (size_t)NPART * BATCH;
    float* pa_hc        = pa_hs + (size_t)NPART * BATCH;

    k_init<<<(NCLS * KP + 255) / 256, 256, 0, stream>>>(ov, own_sum);
    k_norm<<<BATCH, 128, 0, stream>>>(features, f, fb);
    k_meta<<<1, BATCH, 0, stream>>>(labels, mptr, rank, gs, fidx, ov);
    k_conv<<<NBROWS / 4, 256, 0, stream>>>(f, bank, ov, Bm);
    k_batchpos<<<BATCH, 256, 0, stream>>>(f, labels, rank, gs, fidx, psb, cb);
    dim3 g5(BATCH / 128, NCB);
    k_main<<<g5, 256, 0, stream>>>(fb, Bm, labels, own_sum, pa_all, pa_hs, pa_hc);
    k_ownextra<<<BATCH, 256, 0, stream>>>(f, bank, labels, ov, own2);
    k_reduce<<<BATCH, 256, 0, stream>>>(pa_all, pa_hs, pa_hc, all_sum, hard_sum, hard_cnt);
    k_final<<<1, BATCH, 0, stream>>>(own_sum, own2, all_sum, hard_sum, hard_cnt, psb, cb, out);
}